// Round 6
// baseline (326.857 us; speedup 1.0000x reference)
//
#include <hip/hip_runtime.h>

typedef unsigned short u16;
typedef __attribute__((ext_vector_type(8))) short short8;
typedef __attribute__((ext_vector_type(4))) unsigned short u16x4;
typedef __attribute__((ext_vector_type(4))) float f32x4;

#define N_TOKENS 32768
#define EMBED 512
#define NCLS 16
#define NBATCH 8
#define NHEAD 8
#define DHEAD 64

__device__ __forceinline__ u16 f2bf(float f) {
  unsigned u = __float_as_uint(f);
  u += 0x7fffu + ((u >> 16) & 1u);   // RNE
  return (u16)(u >> 16);
}

// ---------------- K/V projection, W-stationary ----------------
// 256 blocks: blk&1 = K/V, 4 f-rows per block (one per wave). Each thread
// register-caches W[fr, ec*8..+8) (read ONCE, coalesced). Loop over the 128
// (b,l) rows: coalesced key/val reads (lanes cover the 2KB row), 8 FMA,
// full-wave shfl reduce. Kills the 64-lines-per-instr W gather of the old
// version (4x request amplification on 256 MB).
__global__ __launch_bounds__(256) void kvproj_kernel(
    const float* __restrict__ key, const float* __restrict__ val,
    const float* __restrict__ Wk, const float* __restrict__ bk,
    const float* __restrict__ Wv, const float* __restrict__ bv,
    float* __restrict__ kproj, float* __restrict__ vproj) {
  const int tid = threadIdx.x;
  const bool isV = blockIdx.x & 1;
  const int fgrp = blockIdx.x >> 1;           // [0,128)
  const int wave = tid >> 6;
  const int ec = tid & 63;
  const int fr = fgrp * 4 + wave;             // [0,512)
  const float* W = (isV ? Wv : Wk) + (size_t)fr * 512 + ec * 8;
  const float4 w0 = *(const float4*)W;
  const float4 w1 = *(const float4*)(W + 4);
  const float* src = isV ? val : key;
  const float bval = (isV ? bv : bk)[fr];
  const int h = fr >> 6, d = fr & 63;

#pragma unroll 4
  for (int r = 0; r < 128; r++) {
    const int b = r >> 4, l = r & 15;
    const float* s = src + (size_t)l * (NBATCH * EMBED) + (size_t)b * EMBED + ec * 8;
    float4 a0 = *(const float4*)s;
    float4 a1 = *(const float4*)(s + 4);
    float acc = a0.x * w0.x + a0.y * w0.y + a0.z * w0.z + a0.w * w0.w +
                a1.x * w1.x + a1.y * w1.y + a1.z * w1.z + a1.w * w1.w;
    acc += __shfl_xor(acc, 1);
    acc += __shfl_xor(acc, 2);
    acc += __shfl_xor(acc, 4);
    acc += __shfl_xor(acc, 8);
    acc += __shfl_xor(acc, 16);
    acc += __shfl_xor(acc, 32);
    if (ec == 0) {
      acc += bval;
      if (!isV) kproj[((size_t)(b * EMBED + fr)) * NCLS + l] = acc;
      else      vproj[(size_t)b * 8192 + (size_t)h * 1024 + l * 64 + d] = acc;
    }
  }
}

// ---------------- merged build: Kq / WoV / sb ----------------
// Kq branch unchanged (coalesced already). WoV branch rewritten: one wave per
// (b,f); lanes = (l, dchunk) so vproj reads are coalesced 64B chunks and Wo
// reads are 4-way broadcast; 2-shfl reduce. Kills the old 64-line/instr
// vproj gather (~16x L2 request amplification, the hidden ~50 us).
__global__ __launch_bounds__(256) void build_all(
    const float* __restrict__ kproj, const float* __restrict__ vproj,
    const float* __restrict__ Wq, const float* __restrict__ bq,
    const float* __restrict__ Wo,
    u16* __restrict__ Kqb, u16* __restrict__ WoVb, float* __restrict__ sb) {
  const int blk = blockIdx.x;
  if (blk < 2048) {
    int t = blk * 256 + threadIdx.x;   // 8*128*512
    int e = t & 511;
    int hl = (t >> 9) & 127;
    int b = t >> 16;
    int h = hl >> 4, l = hl & 15;
    const float* kp = kproj + (size_t)b * 8192 + h * 1024 + l;
    const float* wq = Wq + (size_t)(h * 64) * 512 + e;
    float acc = 0.f;
#pragma unroll 16
    for (int d = 0; d < 64; d++) acc += kp[d * 16] * wq[d * 512];
    Kqb[t] = f2bf(acc);
  } else if (blk < 3072) {
    const int wave = threadIdx.x >> 6;
    const int lane = threadIdx.x & 63;
    const int wgid = (blk - 2048) * 4 + wave;   // [0,4096)
    const int b = wgid >> 9, f = wgid & 511;
    const int l = lane >> 2, c = lane & 3;
    const float* vp = vproj + (size_t)b * 8192 + l * 64 + c * 16;
    const float* wo = Wo + (size_t)f * 512 + c * 16;
#pragma unroll 2
    for (int h = 0; h < 8; h++) {
      const float* v = vp + h * 1024;
      const float* w = wo + h * 64;
      float4 v0 = *(const float4*)v,       w0 = *(const float4*)w;
      float4 v1 = *(const float4*)(v + 4), w1 = *(const float4*)(w + 4);
      float4 v2 = *(const float4*)(v + 8), w2 = *(const float4*)(w + 8);
      float4 v3 = *(const float4*)(v + 12), w3 = *(const float4*)(w + 12);
      float acc = v0.x * w0.x + v0.y * w0.y + v0.z * w0.z + v0.w * w0.w +
                  v1.x * w1.x + v1.y * w1.y + v1.z * w1.z + v1.w * w1.w +
                  v2.x * w2.x + v2.y * w2.y + v2.z * w2.z + v2.w * w2.w +
                  v3.x * w3.x + v3.y * w3.y + v3.z * w3.z + v3.w * w3.w;
      acc += __shfl_xor(acc, 1);
      acc += __shfl_xor(acc, 2);
      if (c == 0) WoVb[(size_t)b * 65536 + (size_t)f * 128 + h * 16 + l] = f2bf(acc);
    }
  } else {
    int t = (blk - 3072) * 256 + threadIdx.x;   // 1024
    int hl = t & 127, b = t >> 7;
    int h = hl >> 4, l = hl & 15;
    const float* kp = kproj + (size_t)b * 8192 + h * 1024 + l;
    const float* q = bq + h * 64;
    float acc = 0.f;
#pragma unroll
    for (int d = 0; d < 64; d++) acc += q[d] * kp[d * 16];
    sb[t] = acc;
  }
}

// ---------------- fused: scores GEMM + softmax + out GEMM ----------------
// v6: BARRIER-FREE phase 1. B fragments load DIRECTLY from the L2-resident
// Kq panel into registers with explicit 1-step double-buffering (no LDS
// staging, no __syncthreads, no vmcnt drains -> memory pipe stays loaded).
// v5's per-step barrier drained vmcnt to 0 every step -> 1.06 TB/s effective
// on 104 MB = the whole 100 us. Wave owns 16 exclusive rows x 128 cols.
// Softmax wave-local; P -> swizzled LDS (one barrier); phase 2 = v5 (WoV
// direct from L2, acc2[4][4], normal stores). Tail-split grid retained.
// Uncapped launch bounds (v5 proved caps => scratch spills).
__global__ __launch_bounds__(256) void fused_attn(
    const float* __restrict__ query, const u16* __restrict__ Kqb,
    const u16* __restrict__ WoVb, const float* __restrict__ sb,
    const float* __restrict__ bo, const int* __restrict__ bidx,
    float* __restrict__ out) {
  __shared__ __align__(16) u16 Ps[64 * 128];      // 16 KB: P, XOR-swizzled
  const int tid = threadIdx.x;
  const int lane = tid & 63;
  const int wave = tid >> 6;
  const int quad = lane >> 4;
  const int l16 = lane & 15;
  const int tileId = blockIdx.x >> 1;
  const int slot = blockIdx.x & 1;
  const int m0 = tileId * 64;
  const int bFirst = bidx[m0];
  const int bLast = bidx[m0 + 63];
  if (slot == 1 && bFirst == bLast) return;   // uniform exit, before any barrier
  const int b0 = (slot == 0) ? bFirst : bFirst + 1;
  const int b1 = (slot == 0) ? bFirst : bLast;

  // per-row batch for predicated stores (phase 2: wave covers all 64 rows)
  int rowb[4][4];
#pragma unroll
  for (int mi = 0; mi < 4; mi++)
#pragma unroll
    for (int r = 0; r < 4; r++) rowb[mi][r] = bidx[m0 + mi * 16 + quad * 4 + r];

  // phase-1 A pointer: wave-exclusive row, quad picks 8-elem k-slice
  const float* pA = query + (size_t)(m0 + wave * 16 + l16) * 512 + quad * 8;

  for (int bb = b0; bb <= b1; bb++) {
    // ---- phase 1: scores = q x Kq[bb]^T, fragments direct from L2 ----
    const u16* Bq = Kqb + (size_t)bb * 65536 + (size_t)l16 * 512 + quad * 8;

    f32x4 acc1[8];
#pragma unroll
    for (int j = 0; j < 8; j++) acc1[j] = (f32x4){0.f, 0.f, 0.f, 0.f};

    // preload step 0
    short8 bc[8];
#pragma unroll
    for (int ni = 0; ni < 8; ni++)
      bc[ni] = *(const short8*)(Bq + (size_t)ni * 16 * 512);
    float4 a0c = *(const float4*)pA;
    float4 a1c = *(const float4*)(pA + 4);

#pragma unroll
    for (int t = 0; t < 16; t++) {
      short8 bn[8];
      float4 a0n, a1n;
      if (t < 15) {                        // prefetch t+1 while t computes
#pragma unroll
        for (int ni = 0; ni < 8; ni++)
          bn[ni] = *(const short8*)(Bq + (size_t)ni * 16 * 512 + (t + 1) * 32);
        a0n = *(const float4*)(pA + (t + 1) * 32);
        a1n = *(const float4*)(pA + (t + 1) * 32 + 4);
      }
      short8 af;
      af[0] = (short)f2bf(a0c.x); af[1] = (short)f2bf(a0c.y);
      af[2] = (short)f2bf(a0c.z); af[3] = (short)f2bf(a0c.w);
      af[4] = (short)f2bf(a1c.x); af[5] = (short)f2bf(a1c.y);
      af[6] = (short)f2bf(a1c.z); af[7] = (short)f2bf(a1c.w);
#pragma unroll
      for (int ni = 0; ni < 8; ni++)
        acc1[ni] = __builtin_amdgcn_mfma_f32_16x16x32_bf16(af, bc[ni], acc1[ni], 0, 0, 0);
      if (t < 15) {
#pragma unroll
        for (int ni = 0; ni < 8; ni++) bc[ni] = bn[ni];
        a0c = a0n; a1c = a1n;
      }
    }

    // ---- softmax over each head's 16 l-cols (16-lane shfl), P -> LDS ----
    float sbv[8];
#pragma unroll
    for (int ni = 0; ni < 8; ni++) sbv[ni] = sb[bb * 128 + ni * 16 + l16];
#pragma unroll
    for (int r = 0; r < 4; r++) {
      const int row = wave * 16 + quad * 4 + r;   // wave-exclusive rows
#pragma unroll
      for (int ni = 0; ni < 8; ni++) {
        float v = acc1[ni][r] + sbv[ni];
        float mx = v;
        mx = fmaxf(mx, __shfl_xor(mx, 1));
        mx = fmaxf(mx, __shfl_xor(mx, 2));
        mx = fmaxf(mx, __shfl_xor(mx, 4));
        mx = fmaxf(mx, __shfl_xor(mx, 8));
        float ev = __expf((v - mx) * 0.125f);   // scale = D^-0.5
        float s = ev;
        s += __shfl_xor(s, 1);
        s += __shfl_xor(s, 2);
        s += __shfl_xor(s, 4);
        s += __shfl_xor(s, 8);
        const int col = ni * 16 + l16;
        Ps[row * 128 + (((col >> 3) ^ (row & 7)) << 3) + (col & 7)] = f2bf(ev / s);
      }
    }
    __syncthreads();   // all P stripes visible

    // ---- phase 2: out[64,512] = P x WoV[bb]^T; wave owns 128 f-cols ----
    const u16* Wv = WoVb + (size_t)bb * 65536;
#pragma unroll
    for (int h2 = 0; h2 < 2; h2++) {
      const int f0 = wave * 128 + h2 * 64;
      f32x4 acc2[4][4];
#pragma unroll
      for (int i = 0; i < 4; i++)
#pragma unroll
        for (int j = 0; j < 4; j++) acc2[i][j] = (f32x4){0.f, 0.f, 0.f, 0.f};
#pragma unroll
      for (int kk = 0; kk < 4; kk++) {
        short8 paf[4], bf2[4];
#pragma unroll
        for (int mi = 0; mi < 4; mi++) {
          const int row = mi * 16 + l16;
          paf[mi] = *(const short8*)&Ps[row * 128 + (((kk * 4 + quad) ^ (row & 7)) << 3)];
        }
#pragma unroll
        for (int ni = 0; ni < 4; ni++) {
          const int fr = f0 + ni * 16 + l16;
          bf2[ni] = *(const short8*)(Wv + (size_t)fr * 128 + kk * 32 + quad * 8);
        }
#pragma unroll
        for (int mi = 0; mi < 4; mi++)
#pragma unroll
          for (int ni = 0; ni < 4; ni++)
            acc2[mi][ni] = __builtin_amdgcn_mfma_f32_16x16x32_bf16(paf[mi], bf2[ni], acc2[mi][ni], 0, 0, 0);
      }
      float bov[4];
#pragma unroll
      for (int ni = 0; ni < 4; ni++) bov[ni] = bo[f0 + ni * 16 + l16];
#pragma unroll
      for (int mi = 0; mi < 4; mi++)
#pragma unroll
        for (int r = 0; r < 4; r++) {
          if (rowb[mi][r] == bb) {
            const size_t row = m0 + mi * 16 + quad * 4 + r;
#pragma unroll
            for (int ni = 0; ni < 4; ni++)
              out[row * 512 + f0 + ni * 16 + l16] = acc2[mi][ni][r] + bov[ni];
          }
        }
    }
    __syncthreads();   // Ps safe to overwrite next bb
  }
}

extern "C" void kernel_launch(void* const* d_in, const int* in_sizes, int n_in,
                              void* d_out, int out_size, void* d_ws, size_t ws_size,
                              hipStream_t stream) {
  const float* query = (const float*)d_in[0];
  const float* keyt = (const float*)d_in[1];
  const float* valt = (const float*)d_in[2];
  const int* bidx = (const int*)d_in[3];
  // d_in[4] = batch_size (scalar, fixed = 8)
  const float* Wq = (const float*)d_in[5];
  const float* bq = (const float*)d_in[6];
  const float* Wk = (const float*)d_in[7];
  const float* bk = (const float*)d_in[8];
  const float* Wv = (const float*)d_in[9];
  const float* bv = (const float*)d_in[10];
  const float* Wo = (const float*)d_in[11];
  const float* bo = (const float*)d_in[12];
  float* out = (float*)d_out;

  // workspace layout (bytes)
  unsigned char* w = (unsigned char*)d_ws;
  float* kproj = (float*)(w + 41943040ull);   //    262,144: [B,H,D,L]
  float* vproj = (float*)(w + 42205184ull);   //    262,144: [B,H,L,D]
  u16* Kqb = (u16*)(w + 42467328ull);         //  1,048,576: [B,128,512] bf16
  u16* WoVb = (u16*)(w + 43515904ull);        //  1,048,576: [B,512,128] bf16
  float* sb = (float*)(w + 44564480ull);      //      4,096: [B,128]

  // 1) K/V projections (fp32, W-stationary)
  kvproj_kernel<<<256, 256, 0, stream>>>(keyt, valt, Wk, bk, Wv, bv, kproj, vproj);

  // 2) fold Wq through k, Wo through v, and sb — one launch
  build_all<<<3076, 256, 0, stream>>>(kproj, vproj, Wq, bq, Wo, Kqb, WoVb, sb);

  // 3) fused: fp32 query -> scores -> softmax -> out (tail-split grid)
  fused_attn<<<N_TOKENS / 64 * 2, 256, 0, stream>>>(query, Kqb, WoVb, sb, bo, bidx, out);
}

// Round 7
// 315.246 us; speedup vs baseline: 1.0368x; 1.0368x over previous
//
#include <hip/hip_runtime.h>

typedef unsigned short u16;
typedef __attribute__((ext_vector_type(8))) short short8;
typedef __attribute__((ext_vector_type(4))) unsigned short u16x4;
typedef __attribute__((ext_vector_type(4))) float f32x4;

#define N_TOKENS 32768
#define EMBED 512
#define NCLS 16
#define NBATCH 8
#define NHEAD 8
#define DHEAD 64

__device__ __forceinline__ u16 f2bf(float f) {
  unsigned u = __float_as_uint(f);
  u += 0x7fffu + ((u >> 16) & 1u);   // RNE
  return (u16)(u >> 16);
}

__device__ __forceinline__ void async16(const u16* g, u16* l) {
  __builtin_amdgcn_global_load_lds(
      (__attribute__((address_space(1))) const unsigned int*)(const void*)g,
      (__attribute__((address_space(3))) unsigned int*)(void*)l,
      16, 0, 0);
}

// Raw barrier: does NOT drain vmcnt (unlike __syncthreads).
#define BARRIER()                                    \
  do {                                               \
    __builtin_amdgcn_sched_barrier(0);               \
    asm volatile("" ::: "memory");                   \
    __builtin_amdgcn_s_barrier();                    \
    asm volatile("" ::: "memory");                   \
    __builtin_amdgcn_sched_barrier(0);               \
  } while (0)

#define WAITV(N) asm volatile("s_waitcnt vmcnt(" #N ")" ::: "memory")

// ---------------- K/V projection, W-stationary (r6, passing, ~fast) ----------------
__global__ __launch_bounds__(256) void kvproj_kernel(
    const float* __restrict__ key, const float* __restrict__ val,
    const float* __restrict__ Wk, const float* __restrict__ bk,
    const float* __restrict__ Wv, const float* __restrict__ bv,
    float* __restrict__ kproj, float* __restrict__ vproj) {
  const int tid = threadIdx.x;
  const bool isV = blockIdx.x & 1;
  const int fgrp = blockIdx.x >> 1;           // [0,128)
  const int wave = tid >> 6;
  const int ec = tid & 63;
  const int fr = fgrp * 4 + wave;             // [0,512)
  const float* W = (isV ? Wv : Wk) + (size_t)fr * 512 + ec * 8;
  const float4 w0 = *(const float4*)W;
  const float4 w1 = *(const float4*)(W + 4);
  const float* src = isV ? val : key;
  const float bval = (isV ? bv : bk)[fr];
  const int h = fr >> 6, d = fr & 63;

#pragma unroll 4
  for (int r = 0; r < 128; r++) {
    const int b = r >> 4, l = r & 15;
    const float* s = src + (size_t)l * (NBATCH * EMBED) + (size_t)b * EMBED + ec * 8;
    float4 a0 = *(const float4*)s;
    float4 a1 = *(const float4*)(s + 4);
    float acc = a0.x * w0.x + a0.y * w0.y + a0.z * w0.z + a0.w * w0.w +
                a1.x * w1.x + a1.y * w1.y + a1.z * w1.z + a1.w * w1.w;
    acc += __shfl_xor(acc, 1);
    acc += __shfl_xor(acc, 2);
    acc += __shfl_xor(acc, 4);
    acc += __shfl_xor(acc, 8);
    acc += __shfl_xor(acc, 16);
    acc += __shfl_xor(acc, 32);
    if (ec == 0) {
      acc += bval;
      if (!isV) kproj[((size_t)(b * EMBED + fr)) * NCLS + l] = acc;
      else      vproj[(size_t)b * 8192 + (size_t)h * 1024 + l * 64 + d] = acc;
    }
  }
}

// ---------------- merged build: Kq / WoV / sb (r6, passing) ----------------
__global__ __launch_bounds__(256) void build_all(
    const float* __restrict__ kproj, const float* __restrict__ vproj,
    const float* __restrict__ Wq, const float* __restrict__ bq,
    const float* __restrict__ Wo,
    u16* __restrict__ Kqb, u16* __restrict__ WoVb, float* __restrict__ sb) {
  const int blk = blockIdx.x;
  if (blk < 2048) {
    int t = blk * 256 + threadIdx.x;   // 8*128*512
    int e = t & 511;
    int hl = (t >> 9) & 127;
    int b = t >> 16;
    int h = hl >> 4, l = hl & 15;
    const float* kp = kproj + (size_t)b * 8192 + h * 1024 + l;
    const float* wq = Wq + (size_t)(h * 64) * 512 + e;
    float acc = 0.f;
#pragma unroll 16
    for (int d = 0; d < 64; d++) acc += kp[d * 16] * wq[d * 512];
    Kqb[t] = f2bf(acc);
  } else if (blk < 3072) {
    const int wave = threadIdx.x >> 6;
    const int lane = threadIdx.x & 63;
    const int wgid = (blk - 2048) * 4 + wave;   // [0,4096)
    const int b = wgid >> 9, f = wgid & 511;
    const int l = lane >> 2, c = lane & 3;
    const float* vp = vproj + (size_t)b * 8192 + l * 64 + c * 16;
    const float* wo = Wo + (size_t)f * 512 + c * 16;
#pragma unroll 2
    for (int h = 0; h < 8; h++) {
      const float* v = vp + h * 1024;
      const float* w = wo + h * 64;
      float4 v0 = *(const float4*)v,       w0 = *(const float4*)w;
      float4 v1 = *(const float4*)(v + 4), w1 = *(const float4*)(w + 4);
      float4 v2 = *(const float4*)(v + 8), w2 = *(const float4*)(w + 8);
      float4 v3 = *(const float4*)(v + 12), w3 = *(const float4*)(w + 12);
      float acc = v0.x * w0.x + v0.y * w0.y + v0.z * w0.z + v0.w * w0.w +
                  v1.x * w1.x + v1.y * w1.y + v1.z * w1.z + v1.w * w1.w +
                  v2.x * w2.x + v2.y * w2.y + v2.z * w2.z + v2.w * w2.w +
                  v3.x * w3.x + v3.y * w3.y + v3.z * w3.z + v3.w * w3.w;
      acc += __shfl_xor(acc, 1);
      acc += __shfl_xor(acc, 2);
      if (c == 0) WoVb[(size_t)b * 65536 + (size_t)f * 128 + h * 16 + l] = f2bf(acc);
    }
  } else {
    int t = (blk - 3072) * 256 + threadIdx.x;   // 1024
    int hl = t & 127, b = t >> 7;
    int h = hl >> 4, l = hl & 15;
    const float* kp = kproj + (size_t)b * 8192 + h * 1024 + l;
    const float* q = bq + h * 64;
    float acc = 0.f;
#pragma unroll
    for (int d = 0; d < 64; d++) acc += q[d] * kp[d * 16];
    sb[t] = acc;
  }
}

// ---------------- fused: scores GEMM + softmax + out GEMM ----------------
// v7 = v5's LDS-staged structure + counted-vmcnt deep pipeline (no per-step
// vmcnt drain). 64-token tiles, tail-split grid, uncapped regs (v5 proved
// caps => spills). Phase 1: Kq panel staged via global_load_lds into a
// 4-slot circular buffer, 3 K-slices in flight; A (fp32 query) prefetched
// into a 3-slot register rotation, fp32->bf16 fused. Per step: raw s_barrier
// + WAITV(4) (issue order B-stage then A-load makes 4 exact; conservative
// under reorder). Full drain only at step 0 of each bb. Softmax -> swizzled
// Ps; phase 2 verbatim v5 (WoV direct from L2, normal stores).
__global__ __launch_bounds__(256) void fused_attn(
    const float* __restrict__ query, const u16* __restrict__ Kqb,
    const u16* __restrict__ WoVb, const float* __restrict__ sb,
    const float* __restrict__ bo, const int* __restrict__ bidx,
    float* __restrict__ out) {
  __shared__ __align__(16) u16 Bs[4][4096];       // 32 KB: Kq k-slices, 4-slot
  __shared__ __align__(16) u16 Ps[64 * 128];      // 16 KB: P, XOR-swizzled
  const int tid = threadIdx.x;
  const int lane = tid & 63;
  const int wave = tid >> 6;
  const int quad = lane >> 4;
  const int l16 = lane & 15;
  const int tileId = blockIdx.x >> 1;
  const int slot = blockIdx.x & 1;
  const int m0 = tileId * 64;
  const int bFirst = bidx[m0];
  const int bLast = bidx[m0 + 63];
  if (slot == 1 && bFirst == bLast) return;   // uniform exit, before any barrier
  const int b0 = (slot == 0) ? bFirst : bFirst + 1;
  const int b1 = (slot == 0) ? bFirst : bLast;

  // staging coords: 512 chunks of 16B per 8KB k-slice; thread owns chunks
  // tid and tid+256. chunk c -> row=c>>2, kpart=c&3; source pre-swizzled.
  const int r0 = tid >> 2, r1 = r0 + 64;
  const int lg0 = (tid & 3) ^ ((r0 >> 1) & 3);
  const int lg1 = (tid & 3) ^ ((r1 >> 1) & 3);
  const size_t boff0 = (size_t)r0 * 512 + lg0 * 8;
  const size_t boff1 = (size_t)r1 * 512 + lg1 * 8;

#define STAGE_B(T, S)                                       \
  do {                                                      \
    async16(Bq + boff0 + (T) * 32, &Bs[S][tid * 8]);        \
    async16(Bq + boff1 + (T) * 32, &Bs[S][tid * 8 + 2048]); \
  } while (0)

  // per-row batch for predicated stores (phase 2: wave covers all 64 rows)
  int rowb[4][4];
#pragma unroll
  for (int mi = 0; mi < 4; mi++)
#pragma unroll
    for (int r = 0; r < 4; r++) rowb[mi][r] = bidx[m0 + mi * 16 + quad * 4 + r];

  // phase-1 A pointer: wave-exclusive row, quad picks 8-elem k-slice
  const float* pA = query + (size_t)(m0 + wave * 16 + l16) * 512 + quad * 8;

  for (int bb = b0; bb <= b1; bb++) {
    const u16* Bq = Kqb + (size_t)bb * 65536;

    // prologue: B0 B1 A0 B2 A1 (3 B-slices + 2 A-slices in flight)
    float4 aS0[2], aS1[2], aS2[2];
    STAGE_B(0, 0);
    STAGE_B(1, 1);
    aS0[0] = *(const float4*)pA;       aS0[1] = *(const float4*)(pA + 4);
    STAGE_B(2, 2);
    aS1[0] = *(const float4*)(pA + 32); aS1[1] = *(const float4*)(pA + 36);

    f32x4 acc1[8];
#pragma unroll
    for (int j = 0; j < 8; j++) acc1[j] = (f32x4){0.f, 0.f, 0.f, 0.f};

#pragma unroll
    for (int t = 0; t < 16; t++) {
      if (t == 0)      { WAITV(0); }   // one full drain per bb: prologue settled
      else if (t <= 13) { WAITV(4); }   // B(t),A(t) done; 2 tiles + 1 A in flight
      else if (t == 14) { WAITV(2); }
      else              { WAITV(0); }
      BARRIER();
      if (t <= 12) {                    // refill slot (t+3)&3; in flight across barriers
        switch ((t + 3) & 3) {
          case 0: STAGE_B(t + 3, 0); break;
          case 1: STAGE_B(t + 3, 1); break;
          case 2: STAGE_B(t + 3, 2); break;
          default: STAGE_B(t + 3, 3); break;
        }
      }
      if (t <= 13) {                    // A(t+2) into rotation slot (t+2)%3
        float4 v0 = *(const float4*)(pA + (t + 2) * 32);
        float4 v1 = *(const float4*)(pA + (t + 2) * 32 + 4);
        switch ((t + 2) % 3) {
          case 0: aS0[0] = v0; aS0[1] = v1; break;
          case 1: aS1[0] = v0; aS1[1] = v1; break;
          default: aS2[0] = v0; aS2[1] = v1; break;
        }
      }
      float4 a0, a1;
      switch (t % 3) {
        case 0: a0 = aS0[0]; a1 = aS0[1]; break;
        case 1: a0 = aS1[0]; a1 = aS1[1]; break;
        default: a0 = aS2[0]; a1 = aS2[1]; break;
      }
      short8 af;
      af[0] = (short)f2bf(a0.x); af[1] = (short)f2bf(a0.y);
      af[2] = (short)f2bf(a0.z); af[3] = (short)f2bf(a0.w);
      af[4] = (short)f2bf(a1.x); af[5] = (short)f2bf(a1.y);
      af[6] = (short)f2bf(a1.z); af[7] = (short)f2bf(a1.w);
      const u16* bs = Bs[t & 3];
#pragma unroll
      for (int ni = 0; ni < 8; ni++) {
        const int rw = ni * 16 + l16;
        short8 bfr = *(const short8*)&bs[rw * 32 + ((quad ^ ((rw >> 1) & 3)) << 3)];
        acc1[ni] = __builtin_amdgcn_mfma_f32_16x16x32_bf16(af, bfr, acc1[ni], 0, 0, 0);
      }
    }

    // ---- softmax over each head's 16 l-cols (16-lane shfl), P -> LDS ----
    float sbv[8];
#pragma unroll
    for (int ni = 0; ni < 8; ni++) sbv[ni] = sb[bb * 128 + ni * 16 + l16];
#pragma unroll
    for (int r = 0; r < 4; r++) {
      const int row = wave * 16 + quad * 4 + r;   // wave-exclusive rows
#pragma unroll
      for (int ni = 0; ni < 8; ni++) {
        float v = acc1[ni][r] + sbv[ni];
        float mx = v;
        mx = fmaxf(mx, __shfl_xor(mx, 1));
        mx = fmaxf(mx, __shfl_xor(mx, 2));
        mx = fmaxf(mx, __shfl_xor(mx, 4));
        mx = fmaxf(mx, __shfl_xor(mx, 8));
        float ev = __expf((v - mx) * 0.125f);   // scale = D^-0.5
        float s = ev;
        s += __shfl_xor(s, 1);
        s += __shfl_xor(s, 2);
        s += __shfl_xor(s, 4);
        s += __shfl_xor(s, 8);
        const int col = ni * 16 + l16;
        Ps[row * 128 + (((col >> 3) ^ (row & 7)) << 3) + (col & 7)] = f2bf(ev / s);
      }
    }
    __syncthreads();   // all P stripes visible (drains everything; once per bb)

    // ---- phase 2: out[64,512] = P x WoV[bb]^T; wave owns 128 f-cols ----
    const u16* Wv = WoVb + (size_t)bb * 65536;
#pragma unroll
    for (int h2 = 0; h2 < 2; h2++) {
      const int f0 = wave * 128 + h2 * 64;
      f32x4 acc2[4][4];
#pragma unroll
      for (int i = 0; i < 4; i++)
#pragma unroll
        for (int j = 0; j < 4; j++) acc2[i][j] = (f32x4){0.f, 0.f, 0.f, 0.f};
#pragma unroll
      for (int kk = 0; kk < 4; kk++) {
        short8 paf[4], bf2[4];
#pragma unroll
        for (int mi = 0; mi < 4; mi++) {
          const int row = mi * 16 + l16;
          paf[mi] = *(const short8*)&Ps[row * 128 + (((kk * 4 + quad) ^ (row & 7)) << 3)];
        }
#pragma unroll
        for (int ni = 0; ni < 4; ni++) {
          const int fr = f0 + ni * 16 + l16;
          bf2[ni] = *(const short8*)(Wv + (size_t)fr * 128 + kk * 32 + quad * 8);
        }
#pragma unroll
        for (int mi = 0; mi < 4; mi++)
#pragma unroll
          for (int ni = 0; ni < 4; ni++)
            acc2[mi][ni] = __builtin_amdgcn_mfma_f32_16x16x32_bf16(paf[mi], bf2[ni], acc2[mi][ni], 0, 0, 0);
      }
      float bov[4];
#pragma unroll
      for (int ni = 0; ni < 4; ni++) bov[ni] = bo[f0 + ni * 16 + l16];
#pragma unroll
      for (int mi = 0; mi < 4; mi++)
#pragma unroll
        for (int r = 0; r < 4; r++) {
          if (rowb[mi][r] == bb) {
            const size_t row = m0 + mi * 16 + quad * 4 + r;
#pragma unroll
            for (int ni = 0; ni < 4; ni++)
              out[row * 512 + f0 + ni * 16 + l16] = acc2[mi][ni][r] + bov[ni];
          }
        }
    }
    __syncthreads();   // Ps/Bs safe to overwrite next bb
  }
#undef STAGE_B
}

extern "C" void kernel_launch(void* const* d_in, const int* in_sizes, int n_in,
                              void* d_out, int out_size, void* d_ws, size_t ws_size,
                              hipStream_t stream) {
  const float* query = (const float*)d_in[0];
  const float* keyt = (const float*)d_in[1];
  const float* valt = (const float*)d_in[2];
  const int* bidx = (const int*)d_in[3];
  // d_in[4] = batch_size (scalar, fixed = 8)
  const float* Wq = (const float*)d_in[5];
  const float* bq = (const float*)d_in[6];
  const float* Wk = (const float*)d_in[7];
  const float* bk = (const float*)d_in[8];
  const float* Wv = (const float*)d_in[9];
  const float* bv = (const float*)d_in[10];
  const float* Wo = (const float*)d_in[11];
  const float* bo = (const float*)d_in[12];
  float* out = (float*)d_out;

  // workspace layout (bytes)
  unsigned char* w = (unsigned char*)d_ws;
  float* kproj = (float*)(w + 41943040ull);   //    262,144: [B,H,D,L]
  float* vproj = (float*)(w + 42205184ull);   //    262,144: [B,H,L,D]
  u16* Kqb = (u16*)(w + 42467328ull);         //  1,048,576: [B,128,512] bf16
  u16* WoVb = (u16*)(w + 43515904ull);        //  1,048,576: [B,512,128] bf16
  float* sb = (float*)(w + 44564480ull);      //      4,096: [B,128]

  // 1) K/V projections (fp32, W-stationary)
  kvproj_kernel<<<256, 256, 0, stream>>>(keyt, valt, Wk, bk, Wv, bv, kproj, vproj);

  // 2) fold Wq through k, Wo through v, and sb — one launch
  build_all<<<3076, 256, 0, stream>>>(kproj, vproj, Wq, bq, Wo, Kqb, WoVb, sb);

  // 3) fused: fp32 query -> scores -> softmax -> out (tail-split grid)
  fused_attn<<<N_TOKENS / 64 * 2, 256, 0, stream>>>(query, Kqb, WoVb, sb, bo, bidx, out);
}